// Round 1
// baseline (975.728 us; speedup 1.0000x reference)
//
#include <hip/hip_runtime.h>

#define HW 16384   // h*w = 128*128
#define C  256
#define D  64
#define NB 16      // batch

__device__ __forceinline__ float fast_exp(float v) {
    return exp2f(v * 1.44269504088896340736f);
}

// ---------------------------------------------------------------------------
// K0: fold conv1 into mk, conv2+BN into mv. Tiny.
//   At[cp][d]  = sum_c mk_w[d][c] * conv1_w[c][cp]        (c'-major for s_load)
//   amk[d]     = sum_c mk_w[d][c] * conv1_b[c]
//   Bm[o][d]   = inv[o] * sum_c conv2_w[o][c] * mv_w[c][d] (o-major)
//   shift[o]   = beta[o] - mean[o]*inv[o]
// ---------------------------------------------------------------------------
__global__ void precompute_kernel(const float* __restrict__ conv1_w,
                                  const float* __restrict__ conv1_b,
                                  const float* __restrict__ mk_w,
                                  const float* __restrict__ mv_w,
                                  const float* __restrict__ conv2_w,
                                  const float* __restrict__ gamma,
                                  const float* __restrict__ beta,
                                  const float* __restrict__ mean,
                                  const float* __restrict__ var,
                                  float* __restrict__ At,
                                  float* __restrict__ amk,
                                  float* __restrict__ Bm,
                                  float* __restrict__ shift)
{
    int gid = blockIdx.x * blockDim.x + threadIdx.x;
    if (gid < C * D) {
        int cp = gid / D, d = gid % D;
        float s = 0.f;
        for (int c = 0; c < C; ++c) s += mk_w[d * C + c] * conv1_w[c * C + cp];
        At[gid] = s;
    } else if (gid < 2 * C * D) {
        int g = gid - C * D;
        int o = g / D, d = g % D;
        float inv = gamma[o] * rsqrtf(var[o] + 1e-5f);
        float s = 0.f;
        for (int c = 0; c < C; ++c) s += conv2_w[o * C + c] * mv_w[c * D + d];
        Bm[g] = s * inv;
    } else if (gid < 2 * C * D + D) {
        int d = gid - 2 * C * D;
        float s = 0.f;
        for (int c = 0; c < C; ++c) s += mk_w[d * C + c] * conv1_b[c];
        amk[d] = s;
    } else if (gid < 2 * C * D + D + C) {
        int o = gid - (2 * C * D + D);
        float inv = gamma[o] * rsqrtf(var[o] + 1e-5f);
        shift[o] = beta[o] - mean[o] * inv;
    }
}

// ---------------------------------------------------------------------------
// K1: logits[b][d][n] = sum_c At[c][d] * x[b][c][n] + amk[d]
// grid (HW/256, NB), 256 threads. Thread owns one n; 64 fp32 accumulators.
// At rows are wave-uniform -> scalar loads; x reads coalesced.
// ---------------------------------------------------------------------------
__global__ __launch_bounds__(256) void logits_kernel(const float* __restrict__ x,
                                                     const float* __restrict__ At,
                                                     const float* __restrict__ amk,
                                                     float* __restrict__ logits)
{
    const int b = blockIdx.y;
    const int n = blockIdx.x * 256 + threadIdx.x;
    const float* xb = x + (size_t)b * C * HW + n;

    float acc[D];
    #pragma unroll
    for (int d = 0; d < D; ++d) acc[d] = amk[d];

    #pragma unroll 4
    for (int c = 0; c < C; ++c) {
        float xv = xb[(size_t)c * HW];
        const float* a = At + c * D;
        #pragma unroll
        for (int d = 0; d < D; ++d) acc[d] += a[d] * xv;
    }

    float* lb = logits + (size_t)b * D * HW + n;
    #pragma unroll
    for (int d = 0; d < D; ++d) lb[(size_t)d * HW] = acc[d];
}

// ---------------------------------------------------------------------------
// K1b: per (b,d) row of 16384: M = max, invS = 1/sum(exp(l - M)).
// One block (256 thr) per row; row held in 64 VGPRs per thread.
// ---------------------------------------------------------------------------
__global__ __launch_bounds__(256) void stats_kernel(const float* __restrict__ logits,
                                                    float* __restrict__ stats)
{
    const int row = blockIdx.x;               // b*D + d
    const float* lr = logits + (size_t)row * HW;
    const int t = threadIdx.x;
    const int lane = t & 63, wid = t >> 6;

    float v[64];
    float m = -3.402823466e+38f;
    #pragma unroll
    for (int i = 0; i < 64; ++i) {
        v[i] = lr[t + i * 256];
        m = fmaxf(m, v[i]);
    }
    #pragma unroll
    for (int off = 1; off < 64; off <<= 1) m = fmaxf(m, __shfl_xor(m, off));

    __shared__ float redm[4];
    if (lane == 0) redm[wid] = m;
    __syncthreads();
    const float bm = fmaxf(fmaxf(redm[0], redm[1]), fmaxf(redm[2], redm[3]));

    float s = 0.f;
    #pragma unroll
    for (int i = 0; i < 64; ++i) s += fast_exp(v[i] - bm);
    #pragma unroll
    for (int off = 1; off < 64; off <<= 1) s += __shfl_xor(s, off);

    __shared__ float reds[4];
    if (lane == 0) reds[wid] = s;
    __syncthreads();
    if (t == 0) {
        float S = reds[0] + reds[1] + reds[2] + reds[3];
        stats[2 * row]     = bm;
        stats[2 * row + 1] = 1.0f / S;
    }
}

// ---------------------------------------------------------------------------
// K3: p[d] = exp(l - M)*invS; column-normalize over d (thread-local!);
//     out[o][n] = relu( sum_d Bm[o][d]*p[d] + shift[o] + x[b][o][n] )
// grid (HW/256, NB), 256 threads, thread owns one n (a full d-column).
// ---------------------------------------------------------------------------
__global__ __launch_bounds__(256) void out_kernel(const float* __restrict__ x,
                                                  const float* __restrict__ logits,
                                                  const float* __restrict__ stats,
                                                  const float* __restrict__ Bm,
                                                  const float* __restrict__ shift,
                                                  float* __restrict__ out)
{
    const int b = blockIdx.y;
    const int n = blockIdx.x * 256 + threadIdx.x;
    const float* lb = logits + (size_t)b * D * HW + n;
    const float* st = stats + 2 * b * D;

    float p[D];
    float colsum = 1e-9f;
    #pragma unroll
    for (int d = 0; d < D; ++d) {
        float M    = st[2 * d];
        float invS = st[2 * d + 1];
        float pv = fast_exp(lb[(size_t)d * HW] - M) * invS;
        p[d] = pv;
        colsum += pv;
    }
    const float r = 1.0f / colsum;
    #pragma unroll
    for (int d = 0; d < D; ++d) p[d] *= r;

    const float* xb = x + (size_t)b * C * HW + n;
    float* ob = out + (size_t)b * C * HW + n;

    for (int o = 0; o < C; ++o) {
        const float* brow = Bm + o * D;
        float acc = 0.f;
        #pragma unroll
        for (int d = 0; d < D; ++d) acc += brow[d] * p[d];
        float vv = acc + shift[o] + xb[(size_t)o * HW];
        ob[(size_t)o * HW] = fmaxf(vv, 0.f);
    }
}

// ---------------------------------------------------------------------------
extern "C" void kernel_launch(void* const* d_in, const int* in_sizes, int n_in,
                              void* d_out, int out_size, void* d_ws, size_t ws_size,
                              hipStream_t stream)
{
    const float* x       = (const float*)d_in[0];
    const float* conv1_w = (const float*)d_in[1];
    const float* conv1_b = (const float*)d_in[2];
    const float* mk_w    = (const float*)d_in[3];
    const float* mv_w    = (const float*)d_in[4];
    const float* conv2_w = (const float*)d_in[5];
    const float* gamma   = (const float*)d_in[6];
    const float* beta    = (const float*)d_in[7];
    const float* mean    = (const float*)d_in[8];
    const float* var     = (const float*)d_in[9];
    float* out = (float*)d_out;

    // workspace layout (floats): small tables first, logits last.
    float* At     = (float*)d_ws;        // C*D     = 16384
    float* amk    = At + C * D;          // D       = 64
    float* Bm     = amk + D;             // C*D     = 16384
    float* shift  = Bm + C * D;          // C       = 256
    float* stats  = shift + C;           // 2*NB*D  = 2048
    float* logits = stats + 2 * NB * D;  // NB*D*HW = 16777216  (~67 MB)

    const int pre_work = 2 * C * D + D + C;            // 33088
    precompute_kernel<<<(pre_work + 255) / 256, 256, 0, stream>>>(
        conv1_w, conv1_b, mk_w, mv_w, conv2_w, gamma, beta, mean, var,
        At, amk, Bm, shift);

    logits_kernel<<<dim3(HW / 256, NB), 256, 0, stream>>>(x, At, amk, logits);

    stats_kernel<<<NB * D, 256, 0, stream>>>(logits, stats);

    out_kernel<<<dim3(HW / 256, NB), 256, 0, stream>>>(x, logits, stats, Bm, shift, out);
}

// Round 2
// 894.702 us; speedup vs baseline: 1.0906x; 1.0906x over previous
//
#include <hip/hip_runtime.h>
#include <hip/hip_bf16.h>

#define HW 16384   // h*w = 128*128
#define C  256
#define D  64
#define NB 16      // batch

__device__ __forceinline__ float fast_exp(float v) {
    return exp2f(v * 1.44269504088896340736f);
}

// ---------------------------------------------------------------------------
// K0: fold conv1 into mk, conv2+BN into mv. Tiny.
//   At[cp][d]  = sum_c mk_w[d][c] * conv1_w[c][cp]
//   amk[d]     = sum_c mk_w[d][c] * conv1_b[c]
//   Bm[o][d]   = inv[o] * sum_c conv2_w[o][c] * mv_w[c][d]
//   shift[o]   = beta[o] - mean[o]*inv[o]
// ---------------------------------------------------------------------------
__global__ void precompute_kernel(const float* __restrict__ conv1_w,
                                  const float* __restrict__ conv1_b,
                                  const float* __restrict__ mk_w,
                                  const float* __restrict__ mv_w,
                                  const float* __restrict__ conv2_w,
                                  const float* __restrict__ gamma,
                                  const float* __restrict__ beta,
                                  const float* __restrict__ mean,
                                  const float* __restrict__ var,
                                  float* __restrict__ At,
                                  float* __restrict__ amk,
                                  float* __restrict__ Bm,
                                  float* __restrict__ shift)
{
    int gid = blockIdx.x * blockDim.x + threadIdx.x;
    if (gid < C * D) {
        int cp = gid / D, d = gid % D;
        float s = 0.f;
        for (int c = 0; c < C; ++c) s += mk_w[d * C + c] * conv1_w[c * C + cp];
        At[gid] = s;
    } else if (gid < 2 * C * D) {
        int g = gid - C * D;
        int o = g / D, d = g % D;
        float inv = gamma[o] * rsqrtf(var[o] + 1e-5f);
        float s = 0.f;
        for (int c = 0; c < C; ++c) s += conv2_w[o * C + c] * mv_w[c * D + d];
        Bm[g] = s * inv;
    } else if (gid < 2 * C * D + D) {
        int d = gid - 2 * C * D;
        float s = 0.f;
        for (int c = 0; c < C; ++c) s += mk_w[d * C + c] * conv1_b[c];
        amk[d] = s;
    } else if (gid < 2 * C * D + D + C) {
        int o = gid - (2 * C * D + D);
        float inv = gamma[o] * rsqrtf(var[o] + 1e-5f);
        shift[o] = beta[o] - mean[o] * inv;
    }
}

// ---------------------------------------------------------------------------
// K1: logits[b][d][n] = sum_c At[c][d] * x[b][c][n] + amk[d]   (stored bf16)
// grid (HW/256, NB), 256 threads; thread owns one n, 64 fp32 accumulators.
// At staged through LDS in 64-row chunks -> broadcast ds_read, no per-lane
// VMEM for the small matrix.
// ---------------------------------------------------------------------------
__global__ __launch_bounds__(256) void logits_kernel(const float* __restrict__ x,
                                                     const float* __restrict__ At,
                                                     const float* __restrict__ amk,
                                                     __hip_bfloat16* __restrict__ logits)
{
    __shared__ float As[64 * D];      // 16 KB: 64 c-rows x 64 d
    const int t = threadIdx.x;
    const int b = blockIdx.y;
    const int n = blockIdx.x * 256 + t;
    const float* xb = x + (size_t)b * C * HW + n;

    float acc[D];
    #pragma unroll
    for (int d = 0; d < D; ++d) acc[d] = amk[d];

    for (int cc = 0; cc < C; cc += 64) {
        const float4* src = (const float4*)(At + cc * D);
        #pragma unroll
        for (int k = 0; k < 4; ++k)
            ((float4*)As)[k * 256 + t] = src[k * 256 + t];
        __syncthreads();

        #pragma unroll 2
        for (int ci = 0; ci < 64; ++ci) {
            float xv = xb[(size_t)(cc + ci) * HW];
            const float* a = As + ci * D;   // wave-uniform -> LDS broadcast
            #pragma unroll
            for (int d = 0; d < D; ++d) acc[d] += a[d] * xv;
        }
        __syncthreads();
    }

    __hip_bfloat16* lb = logits + (size_t)b * D * HW + n;
    #pragma unroll
    for (int d = 0; d < D; ++d) lb[(size_t)d * HW] = __float2bfloat16(acc[d]);
}

// ---------------------------------------------------------------------------
// K2: per (b,d) row of 16384 bf16 logits: M = max, invS = 1/sum(exp(l - M)).
// ---------------------------------------------------------------------------
__global__ __launch_bounds__(256) void stats_kernel(const __hip_bfloat16* __restrict__ logits,
                                                    float* __restrict__ stats)
{
    const int row = blockIdx.x;               // b*D + d
    const __hip_bfloat16* lr = logits + (size_t)row * HW;
    const int t = threadIdx.x;
    const int lane = t & 63, wid = t >> 6;

    float v[64];
    float m = -3.402823466e+38f;
    #pragma unroll
    for (int i = 0; i < 64; ++i) {
        v[i] = __bfloat162float(lr[t + i * 256]);
        m = fmaxf(m, v[i]);
    }
    #pragma unroll
    for (int off = 1; off < 64; off <<= 1) m = fmaxf(m, __shfl_xor(m, off));

    __shared__ float redm[4];
    if (lane == 0) redm[wid] = m;
    __syncthreads();
    const float bm = fmaxf(fmaxf(redm[0], redm[1]), fmaxf(redm[2], redm[3]));

    float s = 0.f;
    #pragma unroll
    for (int i = 0; i < 64; ++i) s += fast_exp(v[i] - bm);
    #pragma unroll
    for (int off = 1; off < 64; off <<= 1) s += __shfl_xor(s, off);

    __shared__ float reds[4];
    if (lane == 0) reds[wid] = s;
    __syncthreads();
    if (t == 0) {
        float S = reds[0] + reds[1] + reds[2] + reds[3];
        stats[2 * row]     = bm;
        stats[2 * row + 1] = 1.0f / S;
    }
}

// ---------------------------------------------------------------------------
// K3: p[d] = exp(l - M)*invS; column-normalize over d (thread-local);
//     out[o][n] = relu( sum_d Bm[o][d]*p[d] + shift[o] + x[b][o][n] )
// Bm staged through LDS in 64-row chunks; shift + stats staged once.
// ---------------------------------------------------------------------------
__global__ __launch_bounds__(256) void out_kernel(const float* __restrict__ x,
                                                  const __hip_bfloat16* __restrict__ logits,
                                                  const float* __restrict__ stats,
                                                  const float* __restrict__ Bm,
                                                  const float* __restrict__ shift,
                                                  float* __restrict__ out)
{
    __shared__ float Bs[64 * D];      // 16 KB chunk of Bm
    __shared__ float Ss[C];           // shift, 1 KB
    __shared__ float Sst[2 * D];      // stats for this b, 512 B

    const int t = threadIdx.x;
    const int b = blockIdx.y;
    const int n = blockIdx.x * 256 + t;

    Ss[t] = shift[t];
    if (t < 2 * D) Sst[t] = stats[2 * b * D + t];
    __syncthreads();

    const __hip_bfloat16* lb = logits + (size_t)b * D * HW + n;

    float p[D];
    float colsum = 1e-9f;
    #pragma unroll 2
    for (int d = 0; d < D; ++d) {
        float M    = Sst[2 * d];
        float invS = Sst[2 * d + 1];
        float pv = fast_exp(__bfloat162float(lb[(size_t)d * HW]) - M) * invS;
        p[d] = pv;
        colsum += pv;
    }
    const float r = 1.0f / colsum;
    #pragma unroll
    for (int d = 0; d < D; ++d) p[d] *= r;

    const float* xb = x + (size_t)b * C * HW + n;
    float* ob = out + (size_t)b * C * HW + n;

    for (int oc = 0; oc < C; oc += 64) {
        const float4* src = (const float4*)(Bm + oc * D);
        #pragma unroll
        for (int k = 0; k < 4; ++k)
            ((float4*)Bs)[k * 256 + t] = src[k * 256 + t];
        __syncthreads();

        #pragma unroll 2
        for (int oi = 0; oi < 64; ++oi) {
            const float* brow = Bs + oi * D;   // wave-uniform -> LDS broadcast
            float acc = 0.f;
            #pragma unroll
            for (int d = 0; d < D; ++d) acc += brow[d] * p[d];
            const int o = oc + oi;
            float vv = acc + Ss[o] + xb[(size_t)o * HW];
            ob[(size_t)o * HW] = fmaxf(vv, 0.f);
        }
        __syncthreads();
    }
}

// ---------------------------------------------------------------------------
extern "C" void kernel_launch(void* const* d_in, const int* in_sizes, int n_in,
                              void* d_out, int out_size, void* d_ws, size_t ws_size,
                              hipStream_t stream)
{
    const float* x       = (const float*)d_in[0];
    const float* conv1_w = (const float*)d_in[1];
    const float* conv1_b = (const float*)d_in[2];
    const float* mk_w    = (const float*)d_in[3];
    const float* mv_w    = (const float*)d_in[4];
    const float* conv2_w = (const float*)d_in[5];
    const float* gamma   = (const float*)d_in[6];
    const float* beta    = (const float*)d_in[7];
    const float* mean    = (const float*)d_in[8];
    const float* var     = (const float*)d_in[9];
    float* out = (float*)d_out;

    // workspace layout: fp32 tables, then bf16 logits.
    float* At     = (float*)d_ws;        // C*D = 16384 floats
    float* amk    = At + C * D;          // D
    float* Bm     = amk + D;             // C*D
    float* shift  = Bm + C * D;          // C
    float* stats  = shift + C;           // 2*NB*D
    __hip_bfloat16* logits = (__hip_bfloat16*)(stats + 2 * NB * D);  // NB*D*HW bf16 (~33.5 MB)

    const int pre_work = 2 * C * D + D + C;
    precompute_kernel<<<(pre_work + 255) / 256, 256, 0, stream>>>(
        conv1_w, conv1_b, mk_w, mv_w, conv2_w, gamma, beta, mean, var,
        At, amk, Bm, shift);

    logits_kernel<<<dim3(HW / 256, NB), 256, 0, stream>>>(x, At, amk, logits);

    stats_kernel<<<NB * D, 256, 0, stream>>>(logits, stats);

    out_kernel<<<dim3(HW / 256, NB), 256, 0, stream>>>(x, logits, stats, Bm, shift, out);
}